// Round 5
// baseline (429.933 us; speedup 1.0000x reference)
//
#include <hip/hip_runtime.h>
#include <hip/hip_bf16.h>
#include <cstdint>

#define I_ 16
#define T_ 64
#define Q_ 197
#define K_ 30
#define H_ 8
#define D_ 64
#define E_ 512

typedef float f32x2 __attribute__((ext_vector_type(2)));
typedef float f32x4 __attribute__((ext_vector_type(4)));
typedef short bf16x8 __attribute__((ext_vector_type(8)));

static constexpr float INV_SQRT_E = 0.044194173824159216f;  // 1/sqrt(512)
static constexpr float C197 = 1.0f / 197.0f;

// workspace offsets (in float units)
#define OFF_QBF   0          // bf16 [I,Q,H,D] 1,613,824 elems = 806,912 floats
#define OFF_KBF   806912     // bf16 [T,K,H,D]   983,040 elems = 491,520 floats
#define OFF_V     1298432    // f32  [T,K,H,D]   983,040
#define OFF_TV    2281472    // f32  [I,Q,H,D] 1,613,824
#define OFF_ASUM  3895296    // [I,T,H,K]        245,760
#define OFF_TASUM 4141056    // [I,T,H,Q]      1,613,824
#define OFF_POUT  5754880    // [I,T,E]          524,288
#define OFF_PTXT  6279168    // [I,T,E]          524,288

// ---------------- K1: projections; q,k -> bf16, v,tv -> f32 ----------------
__global__ __launch_bounds__(512) void proj_kernel(
    const float* __restrict__ image, const float* __restrict__ text,
    const float* __restrict__ Wq, const float* __restrict__ Wk,
    const float* __restrict__ Wv, const float* __restrict__ Wtv,
    float* __restrict__ ws)
{
  const int NQ4 = (I_ * Q_) / 4;   // 788
  const int NT4 = (T_ * K_) / 4;   // 480
  int bb = blockIdx.x;
  const float* X; const float* W; int row0; int mode;
  if (bb < NQ4)             { X = image; W = Wq;  row0 = bb * 4;               mode = 0; }
  else if (bb < NQ4 + NT4)  { X = text;  W = Wk;  row0 = (bb - NQ4) * 4;       mode = 1; }
  else if (bb < NQ4 + 2*NT4){ X = text;  W = Wv;  row0 = (bb - NQ4 - NT4) * 4; mode = 2; }
  else                      { X = image; W = Wtv; row0 = (bb - NQ4 - 2*NT4)*4; mode = 3; }

  __shared__ float s_x[4][E_];        // 8 KB
  __shared__ float s_w[D_][D_ + 1];   // 16.6 KB, +1 pad
  int tid = threadIdx.x;
  for (int idx = tid; idx < D_ * D_; idx += 512) s_w[idx >> 6][idx & 63] = W[idx];
  #pragma unroll
  for (int rr = 0; rr < 4; ++rr) s_x[rr][tid] = X[(size_t)(row0 + rr) * E_ + tid];
  __syncthreads();

  int h = tid >> 6, dout = tid & 63;
  float a0 = 0.f, a1 = 0.f, a2 = 0.f, a3 = 0.f;
  #pragma unroll
  for (int d = 0; d < D_; ++d) {
    float w = s_w[dout][d];
    a0 = fmaf(s_x[0][h * 64 + d], w, a0);
    a1 = fmaf(s_x[1][h * 64 + d], w, a1);
    a2 = fmaf(s_x[2][h * 64 + d], w, a2);
    a3 = fmaf(s_x[3][h * 64 + d], w, a3);
  }
  if (mode <= 1) {
    __hip_bfloat16* Y = (__hip_bfloat16*)(ws + (mode == 0 ? OFF_QBF : OFF_KBF));
    Y[(size_t)(row0 + 0) * E_ + tid] = __float2bfloat16(a0);
    Y[(size_t)(row0 + 1) * E_ + tid] = __float2bfloat16(a1);
    Y[(size_t)(row0 + 2) * E_ + tid] = __float2bfloat16(a2);
    Y[(size_t)(row0 + 3) * E_ + tid] = __float2bfloat16(a3);
  } else {
    float* Y = ws + (mode == 2 ? OFF_V : OFF_TV);
    Y[(size_t)(row0 + 0) * E_ + tid] = a0;
    Y[(size_t)(row0 + 1) * E_ + tid] = a1;
    Y[(size_t)(row0 + 2) * E_ + tid] = a2;
    Y[(size_t)(row0 + 3) * E_ + tid] = a3;
  }
}

// ---------------- K2: register-resident MFMA attention ----------------
// Wave w owns row strips mt in {w, w+4, w+8, w+12} (mt < 13).
// Per lane: lr = lane&15 (col within tile / row of A-frag), lg = lane>>4.
// C/D layout (m89): col = lane&15, row = (lane>>4)*4 + reg.
__global__ __launch_bounds__(256, 4) void attn_kernel(
    const __hip_bfloat16* __restrict__ qbf, const __hip_bfloat16* __restrict__ kbf,
    const int* __restrict__ text_mask,
    float* __restrict__ attn_out, float* __restrict__ tattn_out,
    float* __restrict__ A_sum, float* __restrict__ TA_sum)
{
  int b = blockIdx.x;                  // b = ((i*T)+t)*H + h
  int h = b & 7, t = (b >> 3) & 63, i = b >> 9;
  int tid = threadIdx.x;
  int w = tid >> 6, lane = tid & 63;
  int lr = lane & 15, lg = lane >> 4;

  __shared__ float s_cd[4][32];     // per-wave col denominators
  __shared__ float s_ca[4][32];     // per-wave col A_sum partials
  __shared__ float s_invd[32];

  // per-lane mask bits for cols lr and 16+lr (col 0 is the cls column: always 1)
  int m0 = (lr == 0) ? 1 : text_mask[t * (K_ - 1) + lr - 1];
  int m1 = (lr < 14) ? text_mask[t * (K_ - 1) + 15 + lr] : 0;

  const __hip_bfloat16* qb = qbf + ((size_t)(i * Q_) * H_ + h) * D_;  // row stride 512
  const __hip_bfloat16* kb = kbf + ((size_t)(t * K_) * H_ + h) * D_;

  // B fragments: invariant across mt, load once (rows 30,31 of nt=1 are
  // garbage from adjacent ws data; their outputs are forced to 0 below)
  const bf16x8* bp0 = (const bf16x8*)(kb + (size_t)lr * (H_ * D_) + lg * 8);
  const bf16x8* bp1 = (const bf16x8*)(kb + (size_t)(16 + lr) * (H_ * D_) + lg * 8);
  bf16x8 b00 = bp0[0], b01 = bp0[4];   // nt=0, k-steps 0/1
  bf16x8 b10 = bp1[0], b11 = bp1[4];   // nt=1

  float e0[4][4], e1[4][4], ivr[4][4];
  float cd0 = 0.f, cd1 = 0.f, ca0 = 0.f, ca1 = 0.f;

  #pragma unroll
  for (int j = 0; j < 4; ++j) {
    int mt = w + 4 * j;
    #pragma unroll
    for (int r = 0; r < 4; ++r) { e0[j][r] = 0.f; e1[j][r] = 0.f; ivr[j][r] = 0.f; }
    if (mt < 13) {
      const bf16x8* ap = (const bf16x8*)(qb + (size_t)(mt * 16 + lr) * (H_ * D_) + lg * 8);
      bf16x8 a0 = ap[0], a1 = ap[4];
      f32x4 acc0 = {0.f, 0.f, 0.f, 0.f}, acc1 = {0.f, 0.f, 0.f, 0.f};
      acc0 = __builtin_amdgcn_mfma_f32_16x16x32_bf16(a0, b00, acc0, 0, 0, 0);
      acc0 = __builtin_amdgcn_mfma_f32_16x16x32_bf16(a1, b01, acc0, 0, 0, 0);
      acc1 = __builtin_amdgcn_mfma_f32_16x16x32_bf16(a0, b10, acc1, 0, 0, 0);
      acc1 = __builtin_amdgcn_mfma_f32_16x16x32_bf16(a1, b11, acc1, 0, 0, 0);
      int row0 = mt * 16 + lg * 4;
      float rs[4];
      #pragma unroll
      for (int r = 0; r < 4; ++r) {
        bool vr = (row0 + r) < Q_;
        float v0 = (vr && m0) ? __expf(acc0[r] * INV_SQRT_E) : 0.f;
        float v1 = (vr && m1) ? __expf(acc1[r] * INV_SQRT_E) : 0.f;
        e0[j][r] = v0; e1[j][r] = v1;
        rs[r] = v0 + v1;
      }
      // row sums: reduce over the 16 lr lanes (cols 0-29; invalid cols are 0)
      #pragma unroll
      for (int r = 0; r < 4; ++r) {
        float s = rs[r];
        s += __shfl_xor(s, 1);
        s += __shfl_xor(s, 2);
        s += __shfl_xor(s, 4);
        s += __shfl_xor(s, 8);
        float iv = ((row0 + r) < Q_ && s > 0.f) ? (1.0f / s) : 0.f;
        ivr[j][r] = iv;
        cd0 += e0[j][r]; ca0 += e0[j][r] * iv;
        cd1 += e1[j][r]; ca1 += e1[j][r] * iv;
      }
    }
  }

  // wave-level column reduce over the 4 lg groups
  cd0 += __shfl_xor(cd0, 16); cd0 += __shfl_xor(cd0, 32);
  ca0 += __shfl_xor(ca0, 16); ca0 += __shfl_xor(ca0, 32);
  cd1 += __shfl_xor(cd1, 16); cd1 += __shfl_xor(cd1, 32);
  ca1 += __shfl_xor(ca1, 16); ca1 += __shfl_xor(ca1, 32);
  if (lane < 16) {
    s_cd[w][lr] = cd0; s_cd[w][lr + 16] = cd1;
    s_ca[w][lr] = ca0; s_ca[w][lr + 16] = ca1;
  }
  __syncthreads();

  if (tid < 32) {
    int col = tid;
    float d  = s_cd[0][col] + s_cd[1][col] + s_cd[2][col] + s_cd[3][col];
    float pa = s_ca[0][col] + s_ca[1][col] + s_ca[2][col] + s_ca[3][col];
    int mc = (col == 0) ? 1 : (col < K_ ? text_mask[t * (K_ - 1) + col - 1] : 0);
    s_invd[col] = (mc && d > 0.f) ? (1.0f / d) : 0.f;
    if (col < K_) A_sum[(size_t)b * K_ + col] = pa;
  }
  __syncthreads();

  float ivd0 = s_invd[lr];
  float ivd1 = s_invd[16 + lr];

  float* abase = attn_out  + (size_t)b * (Q_ * K_);
  float* tbase = tattn_out + (size_t)b * (Q_ * K_);
  #pragma unroll
  for (int j = 0; j < 4; ++j) {
    int mt = w + 4 * j;
    if (mt < 13) {
      int row0 = mt * 16 + lg * 4;
      #pragma unroll
      for (int r = 0; r < 4; ++r) {
        int row = row0 + r;
        // text-attention values (masked col -> exactly 1/197)
        float ta0 = m0 ? e0[j][r] * ivd0 : C197;
        float ta1 = (lr < 14) ? (m1 ? e1[j][r] * ivd1 : C197) : 0.f;
        float tsum = ta0 + ta1;
        tsum += __shfl_xor(tsum, 1);
        tsum += __shfl_xor(tsum, 2);
        tsum += __shfl_xor(tsum, 4);
        tsum += __shfl_xor(tsum, 8);
        if (row < Q_) {
          float iv = ivr[j][r];
          __builtin_nontemporal_store(e0[j][r] * iv, abase + row * K_ + lr);
          __builtin_nontemporal_store(ta0,           tbase + row * K_ + lr);
          if (lr < 14) {
            __builtin_nontemporal_store(e1[j][r] * iv, abase + row * K_ + 16 + lr);
            __builtin_nontemporal_store(ta1,           tbase + row * K_ + 16 + lr);
          }
          if (lr == 0) TA_sum[(size_t)b * Q_ + row] = tsum;
        }
      }
    }
  }
}

// ---------------- K3: pooled PV (i2t): P_out[i,t,e] ----------------
__global__ __launch_bounds__(512) void pool_out_kernel(
    const float* __restrict__ A_sum, const float* __restrict__ ws_v,
    float* __restrict__ P_out)
{
  int bt = blockIdx.x;           // i*T + t
  int t = bt & 63;
  int tid = threadIdx.x;
  int h = tid >> 6, d = tid & 63;
  __shared__ float s_A[H_ * K_];
  if (tid < H_ * K_) s_A[tid] = A_sum[(size_t)bt * H_ * K_ + tid];
  __syncthreads();
  float a0 = 0.f, a1 = 0.f;
  #pragma unroll
  for (int kk = 0; kk < K_; kk += 2) {
    a0 = fmaf(s_A[h * K_ + kk],     ws_v[((size_t)(t * K_ + kk)     * H_ + h) * D_ + d], a0);
    a1 = fmaf(s_A[h * K_ + kk + 1], ws_v[((size_t)(t * K_ + kk + 1) * H_ + h) * D_ + d], a1);
  }
  P_out[(size_t)bt * E_ + tid] = (a0 + a1) * (1.0f / 197.0f);
}

// ---------------- K4: pooled (t2i): P_txt[i,t,e] ----------------
__global__ __launch_bounds__(512) void pool_text_kernel(
    const float* __restrict__ TA_sum, const float* __restrict__ ws_tv,
    float* __restrict__ P_txt)
{
  int bt = blockIdx.x;           // i*T + t
  int i = bt >> 6;
  int tid = threadIdx.x;
  int h = tid >> 6, d = tid & 63;
  __shared__ float s_TA[H_ * Q_];
  for (int idx = tid; idx < H_ * Q_; idx += 512) s_TA[idx] = TA_sum[(size_t)bt * H_ * Q_ + idx];
  __syncthreads();
  float a0 = 0.f, a1 = 0.f, a2 = 0.f, a3 = 0.f;
  int qq = 0;
  for (; qq + 4 <= Q_; qq += 4) {
    a0 = fmaf(s_TA[h * Q_ + qq + 0], ws_tv[((size_t)(i * Q_ + qq + 0) * H_ + h) * D_ + d], a0);
    a1 = fmaf(s_TA[h * Q_ + qq + 1], ws_tv[((size_t)(i * Q_ + qq + 1) * H_ + h) * D_ + d], a1);
    a2 = fmaf(s_TA[h * Q_ + qq + 2], ws_tv[((size_t)(i * Q_ + qq + 2) * H_ + h) * D_ + d], a2);
    a3 = fmaf(s_TA[h * Q_ + qq + 3], ws_tv[((size_t)(i * Q_ + qq + 3) * H_ + h) * D_ + d], a3);
  }
  for (; qq < Q_; ++qq)
    a0 = fmaf(s_TA[h * Q_ + qq], ws_tv[((size_t)(i * Q_ + qq) * H_ + h) * D_ + d], a0);
  P_txt[(size_t)bt * E_ + tid] = ((a0 + a1) + (a2 + a3)) * (1.0f / 30.0f);
}

// ---------------- K5: out = A @ W^T + bias (M=1024,N=512,K=512) ----------------
__global__ __launch_bounds__(256) void outproj_kernel(
    const float* __restrict__ A, const float* __restrict__ W,
    const float* __restrict__ bias, float* __restrict__ out)
{
  int r0 = blockIdx.x * 8;
  int eo = blockIdx.y * 256 + threadIdx.x;
  __shared__ float s_A[8][E_];   // 16 KB
  for (int idx = threadIdx.x; idx < 8 * E_; idx += 256)
    s_A[idx >> 9][idx & 511] = A[(size_t)(r0 + (idx >> 9)) * E_ + (idx & 511)];
  __syncthreads();
  float acc[8] = {};
  const float4* wrow = (const float4*)(W + (size_t)eo * E_);
  for (int e4 = 0; e4 < E_ / 4; ++e4) {
    float4 w4 = wrow[e4];
    #pragma unroll
    for (int r = 0; r < 8; ++r) {
      acc[r] = fmaf(s_A[r][e4 * 4 + 0], w4.x, acc[r]);
      acc[r] = fmaf(s_A[r][e4 * 4 + 1], w4.y, acc[r]);
      acc[r] = fmaf(s_A[r][e4 * 4 + 2], w4.z, acc[r]);
      acc[r] = fmaf(s_A[r][e4 * 4 + 3], w4.w, acc[r]);
    }
  }
  float bv = bias[eo];
  #pragma unroll
  for (int r = 0; r < 8; ++r) out[(size_t)(r0 + r) * E_ + eo] = acc[r] + bv;
}

extern "C" void kernel_launch(void* const* d_in, const int* in_sizes, int n_in,
                              void* d_out, int out_size, void* d_ws, size_t ws_size,
                              hipStream_t stream)
{
  const float* image      = (const float*)d_in[0];
  const float* text       = (const float*)d_in[1];
  const int*   tmask      = (const int*)d_in[2];
  const float* Wq         = (const float*)d_in[3];
  const float* Wk         = (const float*)d_in[4];
  const float* Wv         = (const float*)d_in[5];
  const float* W_out      = (const float*)d_in[6];
  const float* b_out      = (const float*)d_in[7];
  const float* Wtv        = (const float*)d_in[8];
  const float* W_out_text = (const float*)d_in[9];
  const float* b_out_text = (const float*)d_in[10];

  float* out = (float*)d_out;
  float* ws  = (float*)d_ws;

  const __hip_bfloat16* qbf = (const __hip_bfloat16*)(ws + OFF_QBF);
  const __hip_bfloat16* kbf = (const __hip_bfloat16*)(ws + OFF_KBF);
  float* v     = ws + OFF_V;
  float* tv    = ws + OFF_TV;
  float* Asum  = ws + OFF_ASUM;
  float* TAsum = ws + OFF_TASUM;
  float* Pout  = ws + OFF_POUT;
  float* Ptxt  = ws + OFF_PTXT;

  float* out_i2t = out;                                   // [I,T,E]
  float* out_t2i = out + (size_t)I_ * T_ * E_;            // [I,T,E]
  float* attn    = out + (size_t)2 * I_ * T_ * E_;        // [I,T,H,Q,K]
  float* tattn   = attn + (size_t)I_ * T_ * H_ * Q_ * K_; // [I,T,H,Q,K]

  proj_kernel<<<(I_*Q_)/4 + 2*((T_*K_)/4) + (I_*Q_)/4, 512, 0, stream>>>(image, text, Wq, Wk, Wv, Wtv, ws);
  attn_kernel<<<I_ * T_ * H_, 256, 0, stream>>>(qbf, kbf, tmask, attn, tattn, Asum, TAsum);
  pool_out_kernel<<<I_ * T_, 512, 0, stream>>>(Asum, v, Pout);
  pool_text_kernel<<<I_ * T_, 512, 0, stream>>>(TAsum, tv, Ptxt);
  outproj_kernel<<<dim3(128, 2), 256, 0, stream>>>(Pout, W_out, b_out, out_i2t);
  outproj_kernel<<<dim3(128, 2), 256, 0, stream>>>(Ptxt, W_out_text, b_out_text, out_t2i);
}

// Round 6
// 245.770 us; speedup vs baseline: 1.7493x; 1.7493x over previous
//
#include <hip/hip_runtime.h>
#include <hip/hip_bf16.h>
#include <cstdint>

#define I_ 16
#define T_ 64
#define Q_ 197
#define K_ 30
#define H_ 8
#define D_ 64
#define E_ 512

typedef float f32x2 __attribute__((ext_vector_type(2)));
typedef float f32x4 __attribute__((ext_vector_type(4)));
typedef short bf16x8 __attribute__((ext_vector_type(8)));

static constexpr float INV_SQRT_E = 0.044194173824159216f;  // 1/sqrt(512)
static constexpr float C197 = 1.0f / 197.0f;

// workspace offsets (in float units)
#define OFF_QBF   0          // bf16 [I,Q,H,D] 1,613,824 elems = 806,912 floats
#define OFF_KBF   806912     // bf16 [T,K,H,D]   983,040 elems = 491,520 floats
#define OFF_V     1298432    // f32  [T,K,H,D]   983,040
#define OFF_TV    2281472    // f32  [I,Q,H,D] 1,613,824
#define OFF_ASUM  3895296    // [I,T,H,K]        245,760
#define OFF_TASUM 4141056    // [I,T,H,Q]      1,613,824
#define OFF_POUT  5754880    // [I,T,E]          524,288
#define OFF_PTXT  6279168    // [I,T,E]          524,288

// ---------------- K1: projections; q,k -> bf16, v,tv -> f32 ----------------
__global__ __launch_bounds__(512) void proj_kernel(
    const float* __restrict__ image, const float* __restrict__ text,
    const float* __restrict__ Wq, const float* __restrict__ Wk,
    const float* __restrict__ Wv, const float* __restrict__ Wtv,
    float* __restrict__ ws)
{
  const int NQ4 = (I_ * Q_) / 4;   // 788
  const int NT4 = (T_ * K_) / 4;   // 480
  int bb = blockIdx.x;
  const float* X; const float* W; int row0; int mode;
  if (bb < NQ4)             { X = image; W = Wq;  row0 = bb * 4;               mode = 0; }
  else if (bb < NQ4 + NT4)  { X = text;  W = Wk;  row0 = (bb - NQ4) * 4;       mode = 1; }
  else if (bb < NQ4 + 2*NT4){ X = text;  W = Wv;  row0 = (bb - NQ4 - NT4) * 4; mode = 2; }
  else                      { X = image; W = Wtv; row0 = (bb - NQ4 - 2*NT4)*4; mode = 3; }

  __shared__ float s_x[4][E_];        // 8 KB
  __shared__ float s_w[D_][D_ + 1];   // 16.6 KB, +1 pad
  int tid = threadIdx.x;
  for (int idx = tid; idx < D_ * D_; idx += 512) s_w[idx >> 6][idx & 63] = W[idx];
  #pragma unroll
  for (int rr = 0; rr < 4; ++rr) s_x[rr][tid] = X[(size_t)(row0 + rr) * E_ + tid];
  __syncthreads();

  int h = tid >> 6, dout = tid & 63;
  float a0 = 0.f, a1 = 0.f, a2 = 0.f, a3 = 0.f;
  #pragma unroll
  for (int d = 0; d < D_; ++d) {
    float w = s_w[dout][d];
    a0 = fmaf(s_x[0][h * 64 + d], w, a0);
    a1 = fmaf(s_x[1][h * 64 + d], w, a1);
    a2 = fmaf(s_x[2][h * 64 + d], w, a2);
    a3 = fmaf(s_x[3][h * 64 + d], w, a3);
  }
  if (mode <= 1) {
    __hip_bfloat16* Y = (__hip_bfloat16*)(ws + (mode == 0 ? OFF_QBF : OFF_KBF));
    Y[(size_t)(row0 + 0) * E_ + tid] = __float2bfloat16(a0);
    Y[(size_t)(row0 + 1) * E_ + tid] = __float2bfloat16(a1);
    Y[(size_t)(row0 + 2) * E_ + tid] = __float2bfloat16(a2);
    Y[(size_t)(row0 + 3) * E_ + tid] = __float2bfloat16(a3);
  } else {
    float* Y = ws + (mode == 2 ? OFF_V : OFF_TV);
    Y[(size_t)(row0 + 0) * E_ + tid] = a0;
    Y[(size_t)(row0 + 1) * E_ + tid] = a1;
    Y[(size_t)(row0 + 2) * E_ + tid] = a2;
    Y[(size_t)(row0 + 3) * E_ + tid] = a3;
  }
}

// ---------------- K2: register MFMA compute + LDS-transposed coalesced epilogue ----------------
// Wave w owns row strips mt in {w, w+4, w+8, w+12} (mt < 13).
// A/B frag: row/col = lane&15, k = (lane>>4)*8 + e. C/D: col = lane&15, row = (lane>>4)*4 + reg.
__global__ __launch_bounds__(256, 5) void attn_kernel(
    const __hip_bfloat16* __restrict__ qbf, const __hip_bfloat16* __restrict__ kbf,
    const int* __restrict__ text_mask,
    float* __restrict__ attn_out, float* __restrict__ tattn_out,
    float* __restrict__ A_sum, float* __restrict__ TA_sum)
{
  int b = blockIdx.x;                  // b = ((i*T)+t)*H + h
  int h = b & 7, t = (b >> 3) & 63, i = b >> 9;
  int tid = threadIdx.x;
  int w = tid >> 6, lane = tid & 63;
  int lr = lane & 15, lg = lane >> 4;

  __shared__ float s_e[208 * 30];    // 24,960 B raw exp tile (masked = 0)
  __shared__ float s_invrow[208];
  __shared__ float s_cd[4][32];
  __shared__ float s_ca[4][32];
  __shared__ float s_invd[32];
  __shared__ int   s_mask[32];

  if (tid < 32) s_mask[tid] = (tid == 0) ? 1 : (tid < K_ ? text_mask[t * (K_ - 1) + tid - 1] : 0);

  // per-lane mask bits for cols lr and 16+lr (col 0 = cls: always 1)
  int m0 = (lr == 0) ? 1 : text_mask[t * (K_ - 1) + lr - 1];
  int m1 = (lr < 14) ? text_mask[t * (K_ - 1) + 15 + lr] : 0;

  const __hip_bfloat16* qb = qbf + ((size_t)(i * Q_) * H_ + h) * D_;  // row stride 512
  const __hip_bfloat16* kb = kbf + ((size_t)(t * K_) * H_ + h) * D_;

  // B fragments: invariant across mt (rows 30,31 of nt=1 are garbage; forced 0 below)
  const bf16x8* bp0 = (const bf16x8*)(kb + (size_t)lr * (H_ * D_) + lg * 8);
  const bf16x8* bp1 = (const bf16x8*)(kb + (size_t)(16 + lr) * (H_ * D_) + lg * 8);
  bf16x8 b00 = bp0[0], b01 = bp0[4];   // nt=0, k-steps 0/1
  bf16x8 b10 = bp1[0], b11 = bp1[4];   // nt=1

  float cd0 = 0.f, cd1 = 0.f, ca0 = 0.f, ca1 = 0.f;

  #pragma unroll
  for (int j = 0; j < 4; ++j) {
    int mt = w + 4 * j;
    if (mt < 13) {
      const bf16x8* ap = (const bf16x8*)(qb + (size_t)(mt * 16 + lr) * (H_ * D_) + lg * 8);
      bf16x8 a0 = ap[0], a1 = ap[4];
      f32x4 acc0 = {0.f, 0.f, 0.f, 0.f}, acc1 = {0.f, 0.f, 0.f, 0.f};
      acc0 = __builtin_amdgcn_mfma_f32_16x16x32_bf16(a0, b00, acc0, 0, 0, 0);
      acc0 = __builtin_amdgcn_mfma_f32_16x16x32_bf16(a1, b01, acc0, 0, 0, 0);
      acc1 = __builtin_amdgcn_mfma_f32_16x16x32_bf16(a0, b10, acc1, 0, 0, 0);
      acc1 = __builtin_amdgcn_mfma_f32_16x16x32_bf16(a1, b11, acc1, 0, 0, 0);
      int row0 = mt * 16 + lg * 4;
      float v0[4], v1[4];
      #pragma unroll
      for (int r = 0; r < 4; ++r) {
        bool vr = (row0 + r) < Q_;
        v0[r] = (vr && m0) ? __expf(acc0[r] * INV_SQRT_E) : 0.f;
        v1[r] = (vr && m1) ? __expf(acc1[r] * INV_SQRT_E) : 0.f;
        // stage raw e into compact [208][30] tile (2-way bank alias: free)
        s_e[(row0 + r) * K_ + lr] = v0[r];
        if (lr < 14) s_e[(row0 + r) * K_ + 16 + lr] = v1[r];
      }
      #pragma unroll
      for (int r = 0; r < 4; ++r) {
        float s = v0[r] + v1[r];
        s += __shfl_xor(s, 1);
        s += __shfl_xor(s, 2);
        s += __shfl_xor(s, 4);
        s += __shfl_xor(s, 8);
        float iv = ((row0 + r) < Q_ && s > 0.f) ? (1.0f / s) : 0.f;
        if (lr == 0) s_invrow[row0 + r] = iv;
        cd0 += v0[r]; ca0 += v0[r] * iv;
        cd1 += v1[r]; ca1 += v1[r] * iv;
      }
    }
  }

  // wave-level column reduce over the 4 lg groups
  cd0 += __shfl_xor(cd0, 16); cd0 += __shfl_xor(cd0, 32);
  ca0 += __shfl_xor(ca0, 16); ca0 += __shfl_xor(ca0, 32);
  cd1 += __shfl_xor(cd1, 16); cd1 += __shfl_xor(cd1, 32);
  ca1 += __shfl_xor(ca1, 16); ca1 += __shfl_xor(ca1, 32);
  if (lane < 16) {
    s_cd[w][lr] = cd0; s_cd[w][lr + 16] = cd1;
    s_ca[w][lr] = ca0; s_ca[w][lr + 16] = ca1;
  }
  __syncthreads();

  if (tid < 32) {
    int col = tid;
    float d  = s_cd[0][col] + s_cd[1][col] + s_cd[2][col] + s_cd[3][col];
    float pa = s_ca[0][col] + s_ca[1][col] + s_ca[2][col] + s_ca[3][col];
    s_invd[col] = (s_mask[col] && d > 0.f) ? (1.0f / d) : 0.f;
    if (col < K_) A_sum[(size_t)b * K_ + col] = pa;
  }
  __syncthreads();

  // TA_sum per row (masked col contributes exactly 1/197)
  if (tid < Q_) {
    float ta = 0.f;
    #pragma unroll
    for (int kk = 0; kk < K_; ++kk) {
      float ev = s_e[tid * K_ + kk];
      ta += s_mask[kk] ? ev * s_invd[kk] : C197;
    }
    TA_sum[(size_t)b * Q_ + tid] = ta;
  }

  // fused coalesced non-temporal copy-out of both tiles
  {
    int r0 = tid >> 4;          // 0..15
    int c2 = tid & 15;          // active when <15
    if (c2 < 15) {
      int mc0 = s_mask[2 * c2], mc1 = s_mask[2 * c2 + 1];
      float inv0 = s_invd[2 * c2], inv1 = s_invd[2 * c2 + 1];
      f32x2* adst = (f32x2*)(attn_out + (size_t)b * (Q_ * K_));
      f32x2* tdst = (f32x2*)(tattn_out + (size_t)b * (Q_ * K_));
      for (int row = r0; row < Q_; row += 16) {
        float ex = s_e[row * K_ + 2 * c2];
        float ey = s_e[row * K_ + 2 * c2 + 1];
        float ir = s_invrow[row];
        f32x2 av  = { ex * ir, ey * ir };
        f32x2 tv2 = { mc0 ? ex * inv0 : C197, mc1 ? ey * inv1 : C197 };
        int o = row * 15 + c2;
        __builtin_nontemporal_store(av, &adst[o]);
        __builtin_nontemporal_store(tv2, &tdst[o]);
      }
    }
  }
}

// ---------------- K3: pooled PV (i2t): P_out[i,t,e] ----------------
__global__ __launch_bounds__(512) void pool_out_kernel(
    const float* __restrict__ A_sum, const float* __restrict__ ws_v,
    float* __restrict__ P_out)
{
  int bt = blockIdx.x;           // i*T + t
  int t = bt & 63;
  int tid = threadIdx.x;
  int h = tid >> 6, d = tid & 63;
  __shared__ float s_A[H_ * K_];
  if (tid < H_ * K_) s_A[tid] = A_sum[(size_t)bt * H_ * K_ + tid];
  __syncthreads();
  float a0 = 0.f, a1 = 0.f;
  #pragma unroll
  for (int kk = 0; kk < K_; kk += 2) {
    a0 = fmaf(s_A[h * K_ + kk],     ws_v[((size_t)(t * K_ + kk)     * H_ + h) * D_ + d], a0);
    a1 = fmaf(s_A[h * K_ + kk + 1], ws_v[((size_t)(t * K_ + kk + 1) * H_ + h) * D_ + d], a1);
  }
  P_out[(size_t)bt * E_ + tid] = (a0 + a1) * (1.0f / 197.0f);
}

// ---------------- K4: pooled (t2i): P_txt[i,t,e] ----------------
__global__ __launch_bounds__(512) void pool_text_kernel(
    const float* __restrict__ TA_sum, const float* __restrict__ ws_tv,
    float* __restrict__ P_txt)
{
  int bt = blockIdx.x;           // i*T + t
  int i = bt >> 6;
  int tid = threadIdx.x;
  int h = tid >> 6, d = tid & 63;
  __shared__ float s_TA[H_ * Q_];
  for (int idx = tid; idx < H_ * Q_; idx += 512) s_TA[idx] = TA_sum[(size_t)bt * H_ * Q_ + idx];
  __syncthreads();
  float a0 = 0.f, a1 = 0.f, a2 = 0.f, a3 = 0.f;
  int qq = 0;
  for (; qq + 4 <= Q_; qq += 4) {
    a0 = fmaf(s_TA[h * Q_ + qq + 0], ws_tv[((size_t)(i * Q_ + qq + 0) * H_ + h) * D_ + d], a0);
    a1 = fmaf(s_TA[h * Q_ + qq + 1], ws_tv[((size_t)(i * Q_ + qq + 1) * H_ + h) * D_ + d], a1);
    a2 = fmaf(s_TA[h * Q_ + qq + 2], ws_tv[((size_t)(i * Q_ + qq + 2) * H_ + h) * D_ + d], a2);
    a3 = fmaf(s_TA[h * Q_ + qq + 3], ws_tv[((size_t)(i * Q_ + qq + 3) * H_ + h) * D_ + d], a3);
  }
  for (; qq < Q_; ++qq)
    a0 = fmaf(s_TA[h * Q_ + qq], ws_tv[((size_t)(i * Q_ + qq) * H_ + h) * D_ + d], a0);
  P_txt[(size_t)bt * E_ + tid] = ((a0 + a1) + (a2 + a3)) * (1.0f / 30.0f);
}

// ---------------- K5: out = A @ W^T + bias (M=1024,N=512,K=512) ----------------
__global__ __launch_bounds__(256) void outproj_kernel(
    const float* __restrict__ A, const float* __restrict__ W,
    const float* __restrict__ bias, float* __restrict__ out)
{
  int r0 = blockIdx.x * 8;
  int eo = blockIdx.y * 256 + threadIdx.x;
  __shared__ float s_A[8][E_];   // 16 KB
  for (int idx = threadIdx.x; idx < 8 * E_; idx += 256)
    s_A[idx >> 9][idx & 511] = A[(size_t)(r0 + (idx >> 9)) * E_ + (idx & 511)];
  __syncthreads();
  float acc[8] = {};
  const float4* wrow = (const float4*)(W + (size_t)eo * E_);
  for (int e4 = 0; e4 < E_ / 4; ++e4) {
    float4 w4 = wrow[e4];
    #pragma unroll
    for (int r = 0; r < 8; ++r) {
      acc[r] = fmaf(s_A[r][e4 * 4 + 0], w4.x, acc[r]);
      acc[r] = fmaf(s_A[r][e4 * 4 + 1], w4.y, acc[r]);
      acc[r] = fmaf(s_A[r][e4 * 4 + 2], w4.z, acc[r]);
      acc[r] = fmaf(s_A[r][e4 * 4 + 3], w4.w, acc[r]);
    }
  }
  float bv = bias[eo];
  #pragma unroll
  for (int r = 0; r < 8; ++r) out[(size_t)(r0 + r) * E_ + eo] = acc[r] + bv;
}

extern "C" void kernel_launch(void* const* d_in, const int* in_sizes, int n_in,
                              void* d_out, int out_size, void* d_ws, size_t ws_size,
                              hipStream_t stream)
{
  const float* image      = (const float*)d_in[0];
  const float* text       = (const float*)d_in[1];
  const int*   tmask      = (const int*)d_in[2];
  const float* Wq         = (const float*)d_in[3];
  const float* Wk         = (const float*)d_in[4];
  const float* Wv         = (const float*)d_in[5];
  const float* W_out      = (const float*)d_in[6];
  const float* b_out      = (const float*)d_in[7];
  const float* Wtv        = (const float*)d_in[8];
  const float* W_out_text = (const float*)d_in[9];
  const float* b_out_text = (const float*)d_in[10];

  float* out = (float*)d_out;
  float* ws  = (float*)d_ws;

  const __hip_bfloat16* qbf = (const __hip_bfloat16*)(ws + OFF_QBF);
  const __hip_bfloat16* kbf = (const __hip_bfloat16*)(ws + OFF_KBF);
  float* v     = ws + OFF_V;
  float* tv    = ws + OFF_TV;
  float* Asum  = ws + OFF_ASUM;
  float* TAsum = ws + OFF_TASUM;
  float* Pout  = ws + OFF_POUT;
  float* Ptxt  = ws + OFF_PTXT;

  float* out_i2t = out;                                   // [I,T,E]
  float* out_t2i = out + (size_t)I_ * T_ * E_;            // [I,T,E]
  float* attn    = out + (size_t)2 * I_ * T_ * E_;        // [I,T,H,Q,K]
  float* tattn   = attn + (size_t)I_ * T_ * H_ * Q_ * K_; // [I,T,H,Q,K]

  proj_kernel<<<(I_*Q_)/4 + 2*((T_*K_)/4) + (I_*Q_)/4, 512, 0, stream>>>(image, text, Wq, Wk, Wv, Wtv, ws);
  attn_kernel<<<I_ * T_ * H_, 256, 0, stream>>>(qbf, kbf, tmask, attn, tattn, Asum, TAsum);
  pool_out_kernel<<<I_ * T_, 512, 0, stream>>>(Asum, v, Pout);
  pool_text_kernel<<<I_ * T_, 512, 0, stream>>>(TAsum, tv, Ptxt);
  outproj_kernel<<<dim3(128, 2), 256, 0, stream>>>(Pout, W_out, b_out, out_i2t);
  outproj_kernel<<<dim3(128, 2), 256, 0, stream>>>(Ptxt, W_out_text, b_out_text, out_t2i);
}

// Round 7
// 212.983 us; speedup vs baseline: 2.0186x; 1.1539x over previous
//
#include <hip/hip_runtime.h>
#include <hip/hip_bf16.h>
#include <cstdint>

#define I_ 16
#define T_ 64
#define Q_ 197
#define K_ 30
#define H_ 8
#define D_ 64
#define E_ 512

typedef float f32x2 __attribute__((ext_vector_type(2)));
typedef float f32x4 __attribute__((ext_vector_type(4)));
typedef short bf16x8 __attribute__((ext_vector_type(8)));

static constexpr float INV_SQRT_E = 0.044194173824159216f;  // 1/sqrt(512)
static constexpr float C197 = 1.0f / 197.0f;

// workspace offsets (in float units)
#define OFF_QBF   0          // bf16 [I,Q,H,D] 1,613,824 elems = 806,912 floats
#define OFF_KBF   806912     // bf16 [T,K,H,D]   983,040 elems = 491,520 floats
#define OFF_V     1298432    // f32  [T,K,H,D]   983,040
#define OFF_TV    2281472    // f32  [I,Q,H,D] 1,613,824
#define OFF_ASUM  3895296    // [I,T,H,K]        245,760
#define OFF_TASUM 4141056    // [I,T,H,Q]      1,613,824
#define OFF_POUT  5754880    // [I,T,E]          524,288
#define OFF_PTXT  6279168    // [I,T,E]          524,288

// ---------------- K1: projections; q,k -> bf16, v,tv -> f32 ----------------
__global__ __launch_bounds__(512) void proj_kernel(
    const float* __restrict__ image, const float* __restrict__ text,
    const float* __restrict__ Wq, const float* __restrict__ Wk,
    const float* __restrict__ Wv, const float* __restrict__ Wtv,
    float* __restrict__ ws)
{
  const int NQ4 = (I_ * Q_) / 4;   // 788
  const int NT4 = (T_ * K_) / 4;   // 480
  int bb = blockIdx.x;
  const float* X; const float* W; int row0; int mode;
  if (bb < NQ4)             { X = image; W = Wq;  row0 = bb * 4;               mode = 0; }
  else if (bb < NQ4 + NT4)  { X = text;  W = Wk;  row0 = (bb - NQ4) * 4;       mode = 1; }
  else if (bb < NQ4 + 2*NT4){ X = text;  W = Wv;  row0 = (bb - NQ4 - NT4) * 4; mode = 2; }
  else                      { X = image; W = Wtv; row0 = (bb - NQ4 - 2*NT4)*4; mode = 3; }

  __shared__ float s_x[4][E_];        // 8 KB
  __shared__ float s_w[D_][D_ + 1];   // 16.6 KB, +1 pad
  int tid = threadIdx.x;
  for (int idx = tid; idx < D_ * D_; idx += 512) s_w[idx >> 6][idx & 63] = W[idx];
  #pragma unroll
  for (int rr = 0; rr < 4; ++rr) s_x[rr][tid] = X[(size_t)(row0 + rr) * E_ + tid];
  __syncthreads();

  int h = tid >> 6, dout = tid & 63;
  float a0 = 0.f, a1 = 0.f, a2 = 0.f, a3 = 0.f;
  #pragma unroll
  for (int d = 0; d < D_; ++d) {
    float w = s_w[dout][d];
    a0 = fmaf(s_x[0][h * 64 + d], w, a0);
    a1 = fmaf(s_x[1][h * 64 + d], w, a1);
    a2 = fmaf(s_x[2][h * 64 + d], w, a2);
    a3 = fmaf(s_x[3][h * 64 + d], w, a3);
  }
  if (mode <= 1) {
    __hip_bfloat16* Y = (__hip_bfloat16*)(ws + (mode == 0 ? OFF_QBF : OFF_KBF));
    Y[(size_t)(row0 + 0) * E_ + tid] = __float2bfloat16(a0);
    Y[(size_t)(row0 + 1) * E_ + tid] = __float2bfloat16(a1);
    Y[(size_t)(row0 + 2) * E_ + tid] = __float2bfloat16(a2);
    Y[(size_t)(row0 + 3) * E_ + tid] = __float2bfloat16(a3);
  } else {
    float* Y = ws + (mode == 2 ? OFF_V : OFF_TV);
    Y[(size_t)(row0 + 0) * E_ + tid] = a0;
    Y[(size_t)(row0 + 1) * E_ + tid] = a1;
    Y[(size_t)(row0 + 2) * E_ + tid] = a2;
    Y[(size_t)(row0 + 3) * E_ + tid] = a3;
  }
}

// ---------------- K2: register MFMA compute + bf16 LDS e-tile + coalesced epilogue ----------------
// Wave w owns row strips mt in {w, w+4, w+8, w+12} (mt < 13).
// A/B frag: row/col = lane&15, k = (lane>>4)*8 + e. C/D: col = lane&15, row = (lane>>4)*4 + reg.
__global__ __launch_bounds__(256, 8) void attn_kernel(
    const __hip_bfloat16* __restrict__ qbf, const __hip_bfloat16* __restrict__ kbf,
    const int* __restrict__ text_mask,
    float* __restrict__ attn_out, float* __restrict__ tattn_out,
    float* __restrict__ A_sum, float* __restrict__ TA_sum)
{
  int b = blockIdx.x;                  // b = ((i*T)+t)*H + h
  int h = b & 7, t = (b >> 3) & 63, i = b >> 9;
  int tid = threadIdx.x;
  int w = tid >> 6, lane = tid & 63;
  int lr = lane & 15, lg = lane >> 4;

  __shared__ __hip_bfloat16 s_e[208 * 30];   // 12,480 B raw exp tile (bf16; masked = 0)
  __shared__ float s_invrow[208];
  __shared__ float s_cd[4][32];
  __shared__ float s_ca[4][32];
  __shared__ float s_invd[32];
  __shared__ int   s_mask[32];

  if (tid < 32) s_mask[tid] = (tid == 0) ? 1 : (tid < K_ ? text_mask[t * (K_ - 1) + tid - 1] : 0);

  // per-lane mask bits for cols lr and 16+lr (col 0 = cls: always 1)
  int m0 = (lr == 0) ? 1 : text_mask[t * (K_ - 1) + lr - 1];
  int m1 = (lr < 14) ? text_mask[t * (K_ - 1) + 15 + lr] : 0;

  const __hip_bfloat16* qb = qbf + ((size_t)(i * Q_) * H_ + h) * D_;  // row stride 512
  const __hip_bfloat16* kb = kbf + ((size_t)(t * K_) * H_ + h) * D_;

  // B fragments: invariant across mt (rows 30,31 of nt=1 are garbage; forced 0 below)
  const bf16x8* bp0 = (const bf16x8*)(kb + (size_t)lr * (H_ * D_) + lg * 8);
  const bf16x8* bp1 = (const bf16x8*)(kb + (size_t)(16 + lr) * (H_ * D_) + lg * 8);
  bf16x8 b00 = bp0[0], b01 = bp0[4];   // nt=0, k-steps 0/1
  bf16x8 b10 = bp1[0], b11 = bp1[4];   // nt=1

  float cd0 = 0.f, cd1 = 0.f, ca0 = 0.f, ca1 = 0.f;

  #pragma unroll
  for (int j = 0; j < 4; ++j) {
    int mt = w + 4 * j;
    if (mt < 13) {
      const bf16x8* ap = (const bf16x8*)(qb + (size_t)(mt * 16 + lr) * (H_ * D_) + lg * 8);
      bf16x8 a0 = ap[0], a1 = ap[4];
      f32x4 acc0 = {0.f, 0.f, 0.f, 0.f}, acc1 = {0.f, 0.f, 0.f, 0.f};
      acc0 = __builtin_amdgcn_mfma_f32_16x16x32_bf16(a0, b00, acc0, 0, 0, 0);
      acc0 = __builtin_amdgcn_mfma_f32_16x16x32_bf16(a1, b01, acc0, 0, 0, 0);
      acc1 = __builtin_amdgcn_mfma_f32_16x16x32_bf16(a0, b10, acc1, 0, 0, 0);
      acc1 = __builtin_amdgcn_mfma_f32_16x16x32_bf16(a1, b11, acc1, 0, 0, 0);
      int row0 = mt * 16 + lg * 4;
      float v0[4], v1[4];
      #pragma unroll
      for (int r = 0; r < 4; ++r) {
        bool vr = (row0 + r) < Q_;
        v0[r] = (vr && m0) ? __expf(acc0[r] * INV_SQRT_E) : 0.f;
        v1[r] = (vr && m1) ? __expf(acc1[r] * INV_SQRT_E) : 0.f;
        s_e[(row0 + r) * K_ + lr] = __float2bfloat16(v0[r]);
        if (lr < 14) s_e[(row0 + r) * K_ + 16 + lr] = __float2bfloat16(v1[r]);
      }
      #pragma unroll
      for (int r = 0; r < 4; ++r) {
        float s = v0[r] + v1[r];
        s += __shfl_xor(s, 1);
        s += __shfl_xor(s, 2);
        s += __shfl_xor(s, 4);
        s += __shfl_xor(s, 8);
        float iv = ((row0 + r) < Q_ && s > 0.f) ? (1.0f / s) : 0.f;
        if (lr == 0) s_invrow[row0 + r] = iv;
        cd0 += v0[r]; ca0 += v0[r] * iv;
        cd1 += v1[r]; ca1 += v1[r] * iv;
      }
    }
  }

  // wave-level column reduce over the 4 lg groups
  cd0 += __shfl_xor(cd0, 16); cd0 += __shfl_xor(cd0, 32);
  ca0 += __shfl_xor(ca0, 16); ca0 += __shfl_xor(ca0, 32);
  cd1 += __shfl_xor(cd1, 16); cd1 += __shfl_xor(cd1, 32);
  ca1 += __shfl_xor(ca1, 16); ca1 += __shfl_xor(ca1, 32);
  if (lane < 16) {
    s_cd[w][lr] = cd0; s_cd[w][lr + 16] = cd1;
    s_ca[w][lr] = ca0; s_ca[w][lr + 16] = ca1;
  }
  __syncthreads();

  if (tid < 32) {
    int col = tid;
    float d  = s_cd[0][col] + s_cd[1][col] + s_cd[2][col] + s_cd[3][col];
    float pa = s_ca[0][col] + s_ca[1][col] + s_ca[2][col] + s_ca[3][col];
    s_invd[col] = (s_mask[col] && d > 0.f) ? (1.0f / d) : 0.f;
    if (col < K_) A_sum[(size_t)b * K_ + col] = pa;
  }
  __syncthreads();

  // TA_sum per row (masked col contributes exactly 1/197)
  if (tid < Q_) {
    float ta = 0.f;
    #pragma unroll
    for (int kk = 0; kk < K_; ++kk) {
      float ev = __bfloat162float(s_e[tid * K_ + kk]);
      ta += s_mask[kk] ? ev * s_invd[kk] : C197;
    }
    TA_sum[(size_t)b * Q_ + tid] = ta;
  }

  // fused coalesced non-temporal copy-out of both tiles
  {
    int r0 = tid >> 4;          // 0..15
    int c2 = tid & 15;          // active when <15
    if (c2 < 15) {
      int mc0 = s_mask[2 * c2], mc1 = s_mask[2 * c2 + 1];
      float inv0 = s_invd[2 * c2], inv1 = s_invd[2 * c2 + 1];
      f32x2* adst = (f32x2*)(attn_out + (size_t)b * (Q_ * K_));
      f32x2* tdst = (f32x2*)(tattn_out + (size_t)b * (Q_ * K_));
      for (int row = r0; row < Q_; row += 16) {
        __hip_bfloat162 ev2 = *(const __hip_bfloat162*)&s_e[row * K_ + 2 * c2];
        float ex = __bfloat162float(ev2.x);
        float ey = __bfloat162float(ev2.y);
        float ir = s_invrow[row];
        f32x2 av  = { ex * ir, ey * ir };
        f32x2 tv2 = { mc0 ? ex * inv0 : C197, mc1 ? ey * inv1 : C197 };
        int o = row * 15 + c2;
        __builtin_nontemporal_store(av, &adst[o]);
        __builtin_nontemporal_store(tv2, &tdst[o]);
      }
    }
  }
}

// ---------------- K3: fused pooled PV (i2t) + pooled t2i ----------------
__global__ __launch_bounds__(512) void pool_fused_kernel(
    const float* __restrict__ A_sum, const float* __restrict__ TA_sum,
    const float* __restrict__ ws_v, const float* __restrict__ ws_tv,
    float* __restrict__ P_out, float* __restrict__ P_txt)
{
  int bt = blockIdx.x;           // i*T + t
  int t = bt & 63;
  int i = bt >> 6;
  int tid = threadIdx.x;
  int h = tid >> 6, d = tid & 63;
  __shared__ float s_A[H_ * K_];     // 240
  __shared__ float s_TA[H_ * Q_];    // 1576
  if (tid < H_ * K_) s_A[tid] = A_sum[(size_t)bt * H_ * K_ + tid];
  for (int idx = tid; idx < H_ * Q_; idx += 512) s_TA[idx] = TA_sum[(size_t)bt * H_ * Q_ + idx];
  __syncthreads();

  // i2t pooled: 30-term dot
  {
    float a0 = 0.f, a1 = 0.f;
    #pragma unroll
    for (int kk = 0; kk < K_; kk += 2) {
      a0 = fmaf(s_A[h * K_ + kk],     ws_v[((size_t)(t * K_ + kk)     * H_ + h) * D_ + d], a0);
      a1 = fmaf(s_A[h * K_ + kk + 1], ws_v[((size_t)(t * K_ + kk + 1) * H_ + h) * D_ + d], a1);
    }
    P_out[(size_t)bt * E_ + tid] = (a0 + a1) * (1.0f / 197.0f);
  }

  // t2i pooled: 197-term dot
  {
    float a0 = 0.f, a1 = 0.f, a2 = 0.f, a3 = 0.f;
    int qq = 0;
    for (; qq + 4 <= Q_; qq += 4) {
      a0 = fmaf(s_TA[h * Q_ + qq + 0], ws_tv[((size_t)(i * Q_ + qq + 0) * H_ + h) * D_ + d], a0);
      a1 = fmaf(s_TA[h * Q_ + qq + 1], ws_tv[((size_t)(i * Q_ + qq + 1) * H_ + h) * D_ + d], a1);
      a2 = fmaf(s_TA[h * Q_ + qq + 2], ws_tv[((size_t)(i * Q_ + qq + 2) * H_ + h) * D_ + d], a2);
      a3 = fmaf(s_TA[h * Q_ + qq + 3], ws_tv[((size_t)(i * Q_ + qq + 3) * H_ + h) * D_ + d], a3);
    }
    for (; qq < Q_; ++qq)
      a0 = fmaf(s_TA[h * Q_ + qq], ws_tv[((size_t)(i * Q_ + qq) * H_ + h) * D_ + d], a0);
    P_txt[(size_t)bt * E_ + tid] = ((a0 + a1) + (a2 + a3)) * (1.0f / 30.0f);
  }
}

// ---------------- K4: both out-projections in one launch (z selects branch) ----------------
__global__ __launch_bounds__(256) void outproj_kernel(
    const float* __restrict__ Pout, const float* __restrict__ Ptxt,
    const float* __restrict__ W_out, const float* __restrict__ W_out_text,
    const float* __restrict__ b_out, const float* __restrict__ b_out_text,
    float* __restrict__ out_i2t, float* __restrict__ out_t2i)
{
  int z = blockIdx.z;
  const float* A    = z ? Ptxt : Pout;
  const float* W    = z ? W_out_text : W_out;
  const float* bias = z ? b_out_text : b_out;
  float* out        = z ? out_t2i : out_i2t;

  int r0 = blockIdx.x * 8;
  int eo = blockIdx.y * 256 + threadIdx.x;
  __shared__ float s_A[8][E_];   // 16 KB
  for (int idx = threadIdx.x; idx < 8 * E_; idx += 256)
    s_A[idx >> 9][idx & 511] = A[(size_t)(r0 + (idx >> 9)) * E_ + (idx & 511)];
  __syncthreads();
  float acc[8] = {};
  const float4* wrow = (const float4*)(W + (size_t)eo * E_);
  for (int e4 = 0; e4 < E_ / 4; ++e4) {
    float4 w4 = wrow[e4];
    #pragma unroll
    for (int r = 0; r < 8; ++r) {
      acc[r] = fmaf(s_A[r][e4 * 4 + 0], w4.x, acc[r]);
      acc[r] = fmaf(s_A[r][e4 * 4 + 1], w4.y, acc[r]);
      acc[r] = fmaf(s_A[r][e4 * 4 + 2], w4.z, acc[r]);
      acc[r] = fmaf(s_A[r][e4 * 4 + 3], w4.w, acc[r]);
    }
  }
  float bv = bias[eo];
  #pragma unroll
  for (int r = 0; r < 8; ++r) out[(size_t)(r0 + r) * E_ + eo] = acc[r] + bv;
}

extern "C" void kernel_launch(void* const* d_in, const int* in_sizes, int n_in,
                              void* d_out, int out_size, void* d_ws, size_t ws_size,
                              hipStream_t stream)
{
  const float* image      = (const float*)d_in[0];
  const float* text       = (const float*)d_in[1];
  const int*   tmask      = (const int*)d_in[2];
  const float* Wq         = (const float*)d_in[3];
  const float* Wk         = (const float*)d_in[4];
  const float* Wv         = (const float*)d_in[5];
  const float* W_out      = (const float*)d_in[6];
  const float* b_out      = (const float*)d_in[7];
  const float* Wtv        = (const float*)d_in[8];
  const float* W_out_text = (const float*)d_in[9];
  const float* b_out_text = (const float*)d_in[10];

  float* out = (float*)d_out;
  float* ws  = (float*)d_ws;

  const __hip_bfloat16* qbf = (const __hip_bfloat16*)(ws + OFF_QBF);
  const __hip_bfloat16* kbf = (const __hip_bfloat16*)(ws + OFF_KBF);
  float* v     = ws + OFF_V;
  float* tv    = ws + OFF_TV;
  float* Asum  = ws + OFF_ASUM;
  float* TAsum = ws + OFF_TASUM;
  float* Pout  = ws + OFF_POUT;
  float* Ptxt  = ws + OFF_PTXT;

  float* out_i2t = out;                                   // [I,T,E]
  float* out_t2i = out + (size_t)I_ * T_ * E_;            // [I,T,E]
  float* attn    = out + (size_t)2 * I_ * T_ * E_;        // [I,T,H,Q,K]
  float* tattn   = attn + (size_t)I_ * T_ * H_ * Q_ * K_; // [I,T,H,Q,K]

  proj_kernel<<<(I_*Q_)/4 + 2*((T_*K_)/4) + (I_*Q_)/4, 512, 0, stream>>>(image, text, Wq, Wk, Wv, Wtv, ws);
  attn_kernel<<<I_ * T_ * H_, 256, 0, stream>>>(qbf, kbf, tmask, attn, tattn, Asum, TAsum);
  pool_fused_kernel<<<I_ * T_, 512, 0, stream>>>(Asum, TAsum, v, tv, Pout, Ptxt);
  outproj_kernel<<<dim3(128, 2, 2), 256, 0, stream>>>(Pout, Ptxt, W_out, W_out_text,
                                                      b_out, b_out_text, out_i2t, out_t2i);
}